// Round 5
// baseline (84.395 us; speedup 1.0000x reference)
//
#include <hip/hip_runtime.h>
#include <math.h>

#define POOLED 7
#define SCALE 0.0625f
#define C_ 256
#define H_ 56
#define W_ 56
#define S_ (H_ * W_)   // 3136
#define NCELL 49

__device__ __forceinline__ float2 fmax2(float2 a, float2 b) {
    return make_float2(fmaxf(a.x, b.x), fmaxf(a.y, b.y));
}

// ---------- Kernel 1: NCHW -> NHWC transpose, 1024 threads, 64x64 tile ----------
// grid = (S/64, C/64, B)
__global__ __launch_bounds__(1024) void nhwc_kernel(
    const float* __restrict__ src, float* __restrict__ dst)
{
    __shared__ float tile[64][65];
    int b = blockIdx.z;
    int sbase = blockIdx.x * 64;
    int cbase = blockIdx.y * 64;
    int tid = threadIdx.x;

    const float* s0 = src + (size_t)b * C_ * S_;
    float* d0 = dst + (size_t)b * S_ * C_;

    {
        int si = tid & 15;         // s-quad
        int c  = tid >> 4;         // 0..63
        float4 v = *(const float4*)(s0 + (size_t)(cbase + c) * S_ + sbase + 4 * si);
        tile[4 * si + 0][c] = v.x;
        tile[4 * si + 1][c] = v.y;
        tile[4 * si + 2][c] = v.z;
        tile[4 * si + 3][c] = v.w;
    }
    __syncthreads();
    {
        int cj = tid & 15;         // c-quad
        int s  = tid >> 4;         // 0..63
        float4 v;
        v.x = tile[s][4 * cj + 0];
        v.y = tile[s][4 * cj + 1];
        v.z = tile[s][4 * cj + 2];
        v.w = tile[s][4 * cj + 3];
        *(float4*)(d0 + (size_t)(sbase + s) * C_ + cbase + 4 * cj) = v;
    }
}

// ---------- Kernel 2: fused pool + output transpose ----------
// grid = (N, 2); block = 512 threads = 8 waves; chalf picks 128 channels.
// Each wave: lane = c-pair (float2), iterates cells wv, wv+8, ... ;
// results staged in LDS tile[128][49], then flat coalesced store of
// out[n, chalf*128 .. chalf*128+127, 0..48] (contiguous 25088 B region).
__global__ __launch_bounds__(512) void pool_fused_kernel(
    const float* __restrict__ t, const float* __restrict__ rois,
    float* __restrict__ out)
{
    __shared__ float tile[128 * NCELL];
    int n     = blockIdx.x;
    int chalf = blockIdx.y;
    int wv    = threadIdx.x >> 6;
    int lane  = threadIdx.x & 63;

    const float* r = rois + n * 5;
    int b  = (int)r[0];
    int x1 = (int)(r[1] * SCALE);
    int y1 = (int)(r[2] * SCALE);
    int x2 = (int)(r[3] * SCALE);
    int y2 = (int)(r[4] * SCALE);
    int rh = y2 - y1 + 1;
    int rw = x2 - x1 + 1;

    const float* base = t + (size_t)b * S_ * C_ + chalf * 128 + 2 * lane;

    for (int cell = wv; cell < NCELL; cell += 8) {
        int ph = cell / POOLED;
        int pw = cell % POOLED;
        int hs = y1 + (ph * rh) / POOLED;
        int he = y1 + ((ph + 1) * rh + POOLED - 1) / POOLED;
        int ws = x1 + (pw * rw) / POOLED;
        int we = x1 + ((pw + 1) * rw + POOLED - 1) / POOLED;

        const float2 NEG = make_float2(-INFINITY, -INFINITY);
        float2 a0 = NEG, a1 = NEG, a2 = NEG, a3 = NEG;
        for (int h = hs; h < he; ++h) {
            const float* hp = base + (size_t)(h * W_) * C_;
            int w = ws;
            for (; w + 3 < we; w += 4) {
                a0 = fmax2(a0, *(const float2*)(hp + (size_t)(w + 0) * C_));
                a1 = fmax2(a1, *(const float2*)(hp + (size_t)(w + 1) * C_));
                a2 = fmax2(a2, *(const float2*)(hp + (size_t)(w + 2) * C_));
                a3 = fmax2(a3, *(const float2*)(hp + (size_t)(w + 3) * C_));
            }
            if (w < we)     a0 = fmax2(a0, *(const float2*)(hp + (size_t)(w + 0) * C_));
            if (w + 1 < we) a1 = fmax2(a1, *(const float2*)(hp + (size_t)(w + 1) * C_));
            if (w + 2 < we) a2 = fmax2(a2, *(const float2*)(hp + (size_t)(w + 2) * C_));
        }
        float2 acc = fmax2(fmax2(a0, a1), fmax2(a2, a3));

        tile[(2 * lane + 0) * NCELL + cell] = acc.x;   // banks: (98*lane+cell)%32 -> 2-way, free
        tile[(2 * lane + 1) * NCELL + cell] = acc.y;
    }
    __syncthreads();

    float* dst = out + (size_t)n * C_ * NCELL + (size_t)chalf * 128 * NCELL;
    #pragma unroll
    for (int k = 0; k < 13; ++k) {
        int f = threadIdx.x + 512 * k;
        if (f < 128 * NCELL) dst[f] = tile[f];
    }
}

// ---------- Fallback if workspace too small ----------
__global__ __launch_bounds__(256) void roipool_direct_kernel(
    const float* __restrict__ feat, const float* __restrict__ rois,
    float* __restrict__ out, int total)
{
    int idx = blockIdx.x * blockDim.x + threadIdx.x;
    if (idx >= total) return;
    int pw = idx % POOLED;
    int ph = (idx / POOLED) % POOLED;
    int c  = (idx / (POOLED * POOLED)) % C_;
    int n  = idx / (POOLED * POOLED * C_);
    const float* r = rois + n * 5;
    int b  = (int)r[0];
    int x1 = (int)(r[1] * SCALE);
    int y1 = (int)(r[2] * SCALE);
    int x2 = (int)(r[3] * SCALE);
    int y2 = (int)(r[4] * SCALE);
    int rh = y2 - y1 + 1;
    int rw = x2 - x1 + 1;
    int hs = y1 + (ph * rh) / POOLED;
    int he = y1 + ((ph + 1) * rh + POOLED - 1) / POOLED;
    int ws = x1 + (pw * rw) / POOLED;
    int we = x1 + ((pw + 1) * rw + POOLED - 1) / POOLED;
    const float* plane = feat + ((size_t)b * C_ + c) * (size_t)S_;
    float m = -INFINITY;
    for (int h = hs; h < he; ++h) {
        const float* row = plane + h * W_;
        for (int w = ws; w < we; ++w) m = fmaxf(m, row[w]);
    }
    out[idx] = m;
}

extern "C" void kernel_launch(void* const* d_in, const int* in_sizes, int n_in,
                              void* d_out, int out_size, void* d_ws, size_t ws_size,
                              hipStream_t stream) {
    const float* feat = (const float*)d_in[0];
    const float* rois = (const float*)d_in[1];
    float* out = (float*)d_out;

    int N = in_sizes[1] / 5;
    size_t need = (size_t)4 * S_ * C_ * sizeof(float);  // 12.85 MB

    if (ws_size >= need) {
        float* t = (float*)d_ws;

        dim3 tgrid(S_ / 64, C_ / 64, 4);
        nhwc_kernel<<<tgrid, 1024, 0, stream>>>(feat, t);

        dim3 pgrid(N, 2);
        pool_fused_kernel<<<pgrid, 512, 0, stream>>>(t, rois, out);
    } else {
        int total = N * C_ * POOLED * POOLED;
        roipool_direct_kernel<<<(total + 255) / 256, 256, 0, stream>>>(feat, rois, out, total);
    }
}

// Round 6
// 37.413 us; speedup vs baseline: 2.2558x; 2.2558x over previous
//
#include <hip/hip_runtime.h>
#include <math.h>

#define POOLED 7
#define SCALE 0.0625f
#define C_ 256
#define H_ 56
#define W_ 56
#define S_ (H_ * W_)   // 3136
#define NCELL 49

__device__ __forceinline__ float4 fmax4(float4 a, float4 b) {
    return make_float4(fmaxf(a.x, b.x), fmaxf(a.y, b.y),
                       fmaxf(a.z, b.z), fmaxf(a.w, b.w));
}

// ---------- Kernel 1: NCHW -> NHWC transpose, 1024 threads, 64x64 tile ----------
// grid = (S/64, C/64, B)
__global__ __launch_bounds__(1024) void nhwc_kernel(
    const float* __restrict__ src, float* __restrict__ dst)
{
    __shared__ float tile[64][65];
    int b = blockIdx.z;
    int sbase = blockIdx.x * 64;
    int cbase = blockIdx.y * 64;
    int tid = threadIdx.x;

    const float* s0 = src + (size_t)b * C_ * S_;
    float* d0 = dst + (size_t)b * S_ * C_;

    {
        int si = tid & 15;         // s-quad
        int c  = tid >> 4;         // 0..63
        float4 v = *(const float4*)(s0 + (size_t)(cbase + c) * S_ + sbase + 4 * si);
        tile[4 * si + 0][c] = v.x;
        tile[4 * si + 1][c] = v.y;
        tile[4 * si + 2][c] = v.z;
        tile[4 * si + 3][c] = v.w;
    }
    __syncthreads();
    {
        int cj = tid & 15;         // c-quad
        int s  = tid >> 4;         // 0..63
        float4 v;
        v.x = tile[s][4 * cj + 0];
        v.y = tile[s][4 * cj + 1];
        v.z = tile[s][4 * cj + 2];
        v.w = tile[s][4 * cj + 3];
        *(float4*)(d0 + (size_t)(sbase + s) * C_ + cbase + 4 * cj) = v;
    }
}

// ---------- Kernel 2: pool. wave = one (n, cell) task; lane = c-quad (float4) ----------
// Block's 4 waves take tasks from 4 different batch quarters -> uniform block time.
// 2x2 (h,w) unroll with clamped duplicate tail (max is idempotent) -> ILP 4 always.
// Writes ws2[(n*49+cell)*256 + c] -> each wave stores 1KB contiguous.
__global__ __launch_bounds__(256) void pool_kernel(
    const float* __restrict__ t, const float* __restrict__ rois,
    float* __restrict__ ws2)
{
    int task = (threadIdx.x >> 6) * 3136 + blockIdx.x;   // [0, 12544)
    int lane = threadIdx.x & 63;

    int n    = task / NCELL;
    int cell = task % NCELL;
    int ph = cell / POOLED;
    int pw = cell % POOLED;

    const float* r = rois + n * 5;
    int b  = (int)r[0];
    int x1 = (int)(r[1] * SCALE);
    int y1 = (int)(r[2] * SCALE);
    int x2 = (int)(r[3] * SCALE);
    int y2 = (int)(r[4] * SCALE);
    int rh = y2 - y1 + 1;
    int rw = x2 - x1 + 1;

    int hs = y1 + (ph * rh) / POOLED;
    int he = y1 + ((ph + 1) * rh + POOLED - 1) / POOLED;
    int ws = x1 + (pw * rw) / POOLED;
    int we = x1 + ((pw + 1) * rw + POOLED - 1) / POOLED;

    const float4* base = (const float4*)(t + (size_t)b * S_ * C_) + lane;

    const float4 NEG = make_float4(-INFINITY, -INFINITY, -INFINITY, -INFINITY);
    float4 a0 = NEG, a1 = NEG, a2 = NEG, a3 = NEG;

    for (int h = hs; h < he; h += 2) {
        int h1 = (h + 1 < he) ? h + 1 : h;
        const float4* hp0 = base + (size_t)(h  * W_) * 64;
        const float4* hp1 = base + (size_t)(h1 * W_) * 64;
        for (int w = ws; w < we; w += 2) {
            int w1 = (w + 1 < we) ? w + 1 : w;
            a0 = fmax4(a0, hp0[(size_t)w  * 64]);
            a1 = fmax4(a1, hp0[(size_t)w1 * 64]);
            a2 = fmax4(a2, hp1[(size_t)w  * 64]);
            a3 = fmax4(a3, hp1[(size_t)w1 * 64]);
        }
    }
    float4 acc = fmax4(fmax4(a0, a1), fmax4(a2, a3));

    *((float4*)(ws2 + ((size_t)task) * C_) + lane) = acc;
}

// ---------- Kernel 3: per-n output transpose (cell, c) -> (c, cell) ----------
// grid = (N, C/64), 256 threads. LDS tile [64 c][49 cell] padded.
__global__ __launch_bounds__(256) void outt_kernel(
    const float* __restrict__ ws2, float* __restrict__ out)
{
    __shared__ float tile[64][51];
    int n = blockIdx.x;
    int cbase = blockIdx.y * 64;
    int tid = threadIdx.x;

    const float* src = ws2 + (size_t)n * NCELL * C_;
    int cl = tid & 63;
    int cell0 = tid >> 6;
    #pragma unroll
    for (int k = 0; k < 13; ++k) {
        int cell = cell0 + 4 * k;
        if (cell < NCELL) tile[cl][cell] = src[(size_t)cell * C_ + cbase + cl];
    }
    __syncthreads();
    float* dst = out + (size_t)n * C_ * NCELL + (size_t)cbase * NCELL;
    #pragma unroll
    for (int k = 0; k < 13; ++k) {
        int f = tid + 256 * k;
        if (f < 64 * NCELL) {
            int c = f / NCELL, cell = f % NCELL;
            dst[f] = tile[c][cell];
        }
    }
}

// ---------- Fallback if workspace too small ----------
__global__ __launch_bounds__(256) void roipool_direct_kernel(
    const float* __restrict__ feat, const float* __restrict__ rois,
    float* __restrict__ out, int total)
{
    int idx = blockIdx.x * blockDim.x + threadIdx.x;
    if (idx >= total) return;
    int pw = idx % POOLED;
    int ph = (idx / POOLED) % POOLED;
    int c  = (idx / (POOLED * POOLED)) % C_;
    int n  = idx / (POOLED * POOLED * C_);
    const float* r = rois + n * 5;
    int b  = (int)r[0];
    int x1 = (int)(r[1] * SCALE);
    int y1 = (int)(r[2] * SCALE);
    int x2 = (int)(r[3] * SCALE);
    int y2 = (int)(r[4] * SCALE);
    int rh = y2 - y1 + 1;
    int rw = x2 - x1 + 1;
    int hs = y1 + (ph * rh) / POOLED;
    int he = y1 + ((ph + 1) * rh + POOLED - 1) / POOLED;
    int ws = x1 + (pw * rw) / POOLED;
    int we = x1 + ((pw + 1) * rw + POOLED - 1) / POOLED;
    const float* plane = feat + ((size_t)b * C_ + c) * (size_t)S_;
    float m = -INFINITY;
    for (int h = hs; h < he; ++h) {
        const float* row = plane + h * W_;
        for (int w = ws; w < we; ++w) m = fmaxf(m, row[w]);
    }
    out[idx] = m;
}

extern "C" void kernel_launch(void* const* d_in, const int* in_sizes, int n_in,
                              void* d_out, int out_size, void* d_ws, size_t ws_size,
                              hipStream_t stream) {
    const float* feat = (const float*)d_in[0];
    const float* rois = (const float*)d_in[1];
    float* out = (float*)d_out;

    int N = in_sizes[1] / 5;
    size_t featElems = (size_t)4 * S_ * C_;
    size_t need = (featElems + (size_t)N * NCELL * C_) * sizeof(float);

    if (ws_size >= need && N == 256) {
        float* t   = (float*)d_ws;
        float* ws2 = (float*)d_ws + featElems;

        dim3 tgrid(S_ / 64, C_ / 64, 4);
        nhwc_kernel<<<tgrid, 1024, 0, stream>>>(feat, t);

        pool_kernel<<<3136, 256, 0, stream>>>(t, rois, ws2);

        dim3 ogrid(N, C_ / 64);
        outt_kernel<<<ogrid, 256, 0, stream>>>(ws2, out);
    } else {
        int total = N * C_ * POOLED * POOLED;
        roipool_direct_kernel<<<(total + 255) / 256, 256, 0, stream>>>(feat, rois, out, total);
    }
}

// Round 7
// 36.374 us; speedup vs baseline: 2.3202x; 1.0286x over previous
//
#include <hip/hip_runtime.h>
#include <math.h>

#define POOLED 7
#define SCALE 0.0625f
#define C_ 256
#define H_ 56
#define W_ 56
#define S_ (H_ * W_)   // 3136
#define NCELL 49

__device__ __forceinline__ float4 fmax4(float4 a, float4 b) {
    return make_float4(fmaxf(a.x, b.x), fmaxf(a.y, b.y),
                       fmaxf(a.z, b.z), fmaxf(a.w, b.w));
}

// ---------- Kernel 1: NCHW -> NHWC transpose, 1024 threads, 64x64 tile ----------
// grid = (S/64, C/64, B)
__global__ __launch_bounds__(1024) void nhwc_kernel(
    const float* __restrict__ src, float* __restrict__ dst)
{
    __shared__ float tile[64][65];
    int b = blockIdx.z;
    int sbase = blockIdx.x * 64;
    int cbase = blockIdx.y * 64;
    int tid = threadIdx.x;

    const float* s0 = src + (size_t)b * C_ * S_;
    float* d0 = dst + (size_t)b * S_ * C_;

    {
        int si = tid & 15;         // s-quad
        int c  = tid >> 4;         // 0..63
        float4 v = *(const float4*)(s0 + (size_t)(cbase + c) * S_ + sbase + 4 * si);
        tile[4 * si + 0][c] = v.x;
        tile[4 * si + 1][c] = v.y;
        tile[4 * si + 2][c] = v.z;
        tile[4 * si + 3][c] = v.w;
    }
    __syncthreads();
    {
        int cj = tid & 15;         // c-quad
        int s  = tid >> 4;         // 0..63
        float4 v;
        v.x = tile[s][4 * cj + 0];
        v.y = tile[s][4 * cj + 1];
        v.z = tile[s][4 * cj + 2];
        v.w = tile[s][4 * cj + 3];
        *(float4*)(d0 + (size_t)(sbase + s) * C_ + cbase + 4 * cj) = v;
    }
}

// ---------- Kernel 2: pool. wave = one (n, cell) task; lane = c-quad (float4) ----------
// XCD swizzle: 3136 = 8 * 392; consecutive tasks (cells of same RoI, which share
// feature rows) land on the same XCD's L2. Waves of a block still take tasks from
// 4 different batch quarters -> uniform block duration.
// Per row: 4-wide independent load batches + 3-slot remainder, 7 acc chains.
__global__ __launch_bounds__(256) void pool_kernel(
    const float* __restrict__ t, const float* __restrict__ rois,
    float* __restrict__ ws2)
{
    int bid  = blockIdx.x;
    int swz  = (bid & 7) * 392 + (bid >> 3);          // bijective XCD chunking
    int task = (threadIdx.x >> 6) * 3136 + swz;       // [0, 12544)
    int lane = threadIdx.x & 63;

    int n    = task / NCELL;
    int cell = task % NCELL;
    int ph = cell / POOLED;
    int pw = cell % POOLED;

    const float* r = rois + n * 5;
    int b  = (int)r[0];
    int x1 = (int)(r[1] * SCALE);
    int y1 = (int)(r[2] * SCALE);
    int x2 = (int)(r[3] * SCALE);
    int y2 = (int)(r[4] * SCALE);
    int rh = y2 - y1 + 1;
    int rw = x2 - x1 + 1;

    int hs = y1 + (ph * rh) / POOLED;
    int he = y1 + ((ph + 1) * rh + POOLED - 1) / POOLED;
    int ws = x1 + (pw * rw) / POOLED;
    int we = x1 + ((pw + 1) * rw + POOLED - 1) / POOLED;
    int nh = he - hs;
    int nw = we - ws;

    const float4* p0 = (const float4*)(t + (size_t)b * S_ * C_) + lane
                       + (size_t)(hs * W_ + ws) * 64;

    const float4 NEG = make_float4(-INFINITY, -INFINITY, -INFINITY, -INFINITY);
    float4 a0 = NEG, a1 = NEG, a2 = NEG, a3 = NEG, a4 = NEG, a5 = NEG, a6 = NEG;

    for (int h = 0; h < nh; ++h) {
        const float4* hp = p0 + (size_t)h * (W_ * 64);
        int w = 0;
        for (; w + 4 <= nw; w += 4) {
            a0 = fmax4(a0, hp[(w + 0) * 64]);
            a1 = fmax4(a1, hp[(w + 1) * 64]);
            a2 = fmax4(a2, hp[(w + 2) * 64]);
            a3 = fmax4(a3, hp[(w + 3) * 64]);
        }
        if (w     < nw) a4 = fmax4(a4, hp[(w + 0) * 64]);
        if (w + 1 < nw) a5 = fmax4(a5, hp[(w + 1) * 64]);
        if (w + 2 < nw) a6 = fmax4(a6, hp[(w + 2) * 64]);
    }
    float4 acc = fmax4(fmax4(fmax4(a0, a1), fmax4(a2, a3)),
                       fmax4(fmax4(a4, a5), a6));

    *((float4*)(ws2 + (size_t)task * C_) + lane) = acc;
}

// ---------- Kernel 3: per-n output transpose (cell, c) -> (c, cell) ----------
// grid = (N, C/64), 256 threads. LDS tile [64 c][49 cell] padded.
__global__ __launch_bounds__(256) void outt_kernel(
    const float* __restrict__ ws2, float* __restrict__ out)
{
    __shared__ float tile[64][51];
    int n = blockIdx.x;
    int cbase = blockIdx.y * 64;
    int tid = threadIdx.x;

    const float* src = ws2 + (size_t)n * NCELL * C_;
    int cl = tid & 63;
    int cell0 = tid >> 6;
    #pragma unroll
    for (int k = 0; k < 13; ++k) {
        int cell = cell0 + 4 * k;
        if (cell < NCELL) tile[cl][cell] = src[(size_t)cell * C_ + cbase + cl];
    }
    __syncthreads();
    float* dst = out + (size_t)n * C_ * NCELL + (size_t)cbase * NCELL;
    #pragma unroll
    for (int k = 0; k < 13; ++k) {
        int f = tid + 256 * k;
        if (f < 64 * NCELL) {
            int c = f / NCELL, cell = f % NCELL;
            dst[f] = tile[c][cell];
        }
    }
}

// ---------- Fallback if workspace too small ----------
__global__ __launch_bounds__(256) void roipool_direct_kernel(
    const float* __restrict__ feat, const float* __restrict__ rois,
    float* __restrict__ out, int total)
{
    int idx = blockIdx.x * blockDim.x + threadIdx.x;
    if (idx >= total) return;
    int pw = idx % POOLED;
    int ph = (idx / POOLED) % POOLED;
    int c  = (idx / (POOLED * POOLED)) % C_;
    int n  = idx / (POOLED * POOLED * C_);
    const float* r = rois + n * 5;
    int b  = (int)r[0];
    int x1 = (int)(r[1] * SCALE);
    int y1 = (int)(r[2] * SCALE);
    int x2 = (int)(r[3] * SCALE);
    int y2 = (int)(r[4] * SCALE);
    int rh = y2 - y1 + 1;
    int rw = x2 - x1 + 1;
    int hs = y1 + (ph * rh) / POOLED;
    int he = y1 + ((ph + 1) * rh + POOLED - 1) / POOLED;
    int ws = x1 + (pw * rw) / POOLED;
    int we = x1 + ((pw + 1) * rw + POOLED - 1) / POOLED;
    const float* plane = feat + ((size_t)b * C_ + c) * (size_t)S_;
    float m = -INFINITY;
    for (int h = hs; h < he; ++h) {
        const float* row = plane + h * W_;
        for (int w = ws; w < we; ++w) m = fmaxf(m, row[w]);
    }
    out[idx] = m;
}

extern "C" void kernel_launch(void* const* d_in, const int* in_sizes, int n_in,
                              void* d_out, int out_size, void* d_ws, size_t ws_size,
                              hipStream_t stream) {
    const float* feat = (const float*)d_in[0];
    const float* rois = (const float*)d_in[1];
    float* out = (float*)d_out;

    int N = in_sizes[1] / 5;
    size_t featElems = (size_t)4 * S_ * C_;
    size_t need = (featElems + (size_t)N * NCELL * C_) * sizeof(float);

    if (ws_size >= need && N == 256) {
        float* t   = (float*)d_ws;
        float* ws2 = (float*)d_ws + featElems;

        dim3 tgrid(S_ / 64, C_ / 64, 4);
        nhwc_kernel<<<tgrid, 1024, 0, stream>>>(feat, t);

        pool_kernel<<<3136, 256, 0, stream>>>(t, rois, ws2);

        dim3 ogrid(N, C_ / 64);
        outt_kernel<<<ogrid, 256, 0, stream>>>(ws2, out);
    } else {
        int total = N * C_ * POOLED * POOLED;
        roipool_direct_kernel<<<(total + 255) / 256, 256, 0, stream>>>(feat, rois, out, total);
    }
}

// Round 8
// 35.824 us; speedup vs baseline: 2.3558x; 1.0154x over previous
//
#include <hip/hip_runtime.h>
#include <math.h>

#define POOLED 7
#define SCALE 0.0625f
#define C_ 256
#define H_ 56
#define W_ 56
#define S_ (H_ * W_)   // 3136
#define NCELL 49

__device__ __forceinline__ float4 fmax4(float4 a, float4 b) {
    return make_float4(fmaxf(a.x, b.x), fmaxf(a.y, b.y),
                       fmaxf(a.z, b.z), fmaxf(a.w, b.w));
}

// ---------- Kernel 1: NCHW -> NHWC transpose, 1024 threads, 64x64 tile ----------
// grid = (S/64, C/64, B)
__global__ __launch_bounds__(1024) void nhwc_kernel(
    const float* __restrict__ src, float* __restrict__ dst)
{
    __shared__ float tile[64][65];
    int b = blockIdx.z;
    int sbase = blockIdx.x * 64;
    int cbase = blockIdx.y * 64;
    int tid = threadIdx.x;

    const float* s0 = src + (size_t)b * C_ * S_;
    float* d0 = dst + (size_t)b * S_ * C_;

    {
        int si = tid & 15;         // s-quad
        int c  = tid >> 4;         // 0..63
        float4 v = *(const float4*)(s0 + (size_t)(cbase + c) * S_ + sbase + 4 * si);
        tile[4 * si + 0][c] = v.x;
        tile[4 * si + 1][c] = v.y;
        tile[4 * si + 2][c] = v.z;
        tile[4 * si + 3][c] = v.w;
    }
    __syncthreads();
    {
        int cj = tid & 15;         // c-quad
        int s  = tid >> 4;         // 0..63
        float4 v;
        v.x = tile[s][4 * cj + 0];
        v.y = tile[s][4 * cj + 1];
        v.z = tile[s][4 * cj + 2];
        v.w = tile[s][4 * cj + 3];
        *(float4*)(d0 + (size_t)(sbase + s) * C_ + cbase + 4 * cj) = v;
    }
}

// ---------- Kernel 2: pool. wave = one (n, cell) task; lane = c-quad (float4) ----------
// XCD swizzle: consecutive tasks (cells of same RoI) -> same XCD L2.
// Inner loop: 2-row x 4-col batches = 8 independent loads per iteration, 8 acc
// chains; tails use clamped duplicate indices (max is idempotent, dup = L1 hit).
__global__ __launch_bounds__(256) void pool_kernel(
    const float* __restrict__ t, const float* __restrict__ rois,
    float* __restrict__ ws2)
{
    int bid  = blockIdx.x;
    int swz  = (bid & 7) * 392 + (bid >> 3);          // bijective XCD chunking
    int task = (threadIdx.x >> 6) * 3136 + swz;       // [0, 12544)
    int lane = threadIdx.x & 63;

    int n    = task / NCELL;
    int cell = task % NCELL;
    int ph = cell / POOLED;
    int pw = cell % POOLED;

    const float* r = rois + n * 5;
    int b  = (int)r[0];
    int x1 = (int)(r[1] * SCALE);
    int y1 = (int)(r[2] * SCALE);
    int x2 = (int)(r[3] * SCALE);
    int y2 = (int)(r[4] * SCALE);
    int rh = y2 - y1 + 1;
    int rw = x2 - x1 + 1;

    int hs = y1 + (ph * rh) / POOLED;
    int he = y1 + ((ph + 1) * rh + POOLED - 1) / POOLED;
    int ws = x1 + (pw * rw) / POOLED;
    int we = x1 + ((pw + 1) * rw + POOLED - 1) / POOLED;
    int nh = he - hs;
    int nw = we - ws;

    const float4* p0 = (const float4*)(t + (size_t)b * S_ * C_) + lane
                       + (size_t)(hs * W_ + ws) * 64;

    const float4 NEG = make_float4(-INFINITY, -INFINITY, -INFINITY, -INFINITY);
    float4 a0 = NEG, a1 = NEG, a2 = NEG, a3 = NEG;
    float4 a4 = NEG, a5 = NEG, a6 = NEG, a7 = NEG;

    for (int h = 0; h < nh; h += 2) {
        int h1 = (h + 1 < nh) ? h + 1 : h;
        const float4* hp0 = p0 + (size_t)h  * (W_ * 64);
        const float4* hp1 = p0 + (size_t)h1 * (W_ * 64);
        for (int w = 0; w < nw; w += 4) {
            int w1 = (w + 1 < nw) ? w + 1 : w;
            int w2 = (w + 2 < nw) ? w + 2 : w;
            int w3 = (w + 3 < nw) ? w + 3 : w;
            a0 = fmax4(a0, hp0[(size_t)w  * 64]);
            a1 = fmax4(a1, hp0[(size_t)w1 * 64]);
            a2 = fmax4(a2, hp0[(size_t)w2 * 64]);
            a3 = fmax4(a3, hp0[(size_t)w3 * 64]);
            a4 = fmax4(a4, hp1[(size_t)w  * 64]);
            a5 = fmax4(a5, hp1[(size_t)w1 * 64]);
            a6 = fmax4(a6, hp1[(size_t)w2 * 64]);
            a7 = fmax4(a7, hp1[(size_t)w3 * 64]);
        }
    }
    float4 acc = fmax4(fmax4(fmax4(a0, a1), fmax4(a2, a3)),
                       fmax4(fmax4(a4, a5), fmax4(a6, a7)));

    *((float4*)(ws2 + (size_t)task * C_) + lane) = acc;
}

// ---------- Kernel 3: per-n output transpose (cell, c) -> (c, cell) ----------
// grid = (N, C/64), 256 threads. LDS tile [64 c][49 cell] padded.
__global__ __launch_bounds__(256) void outt_kernel(
    const float* __restrict__ ws2, float* __restrict__ out)
{
    __shared__ float tile[64][51];
    int n = blockIdx.x;
    int cbase = blockIdx.y * 64;
    int tid = threadIdx.x;

    const float* src = ws2 + (size_t)n * NCELL * C_;
    int cl = tid & 63;
    int cell0 = tid >> 6;
    #pragma unroll
    for (int k = 0; k < 13; ++k) {
        int cell = cell0 + 4 * k;
        if (cell < NCELL) tile[cl][cell] = src[(size_t)cell * C_ + cbase + cl];
    }
    __syncthreads();
    float* dst = out + (size_t)n * C_ * NCELL + (size_t)cbase * NCELL;
    #pragma unroll
    for (int k = 0; k < 13; ++k) {
        int f = tid + 256 * k;
        if (f < 64 * NCELL) {
            int c = f / NCELL, cell = f % NCELL;
            dst[f] = tile[c][cell];
        }
    }
}

// ---------- Fallback if workspace too small ----------
__global__ __launch_bounds__(256) void roipool_direct_kernel(
    const float* __restrict__ feat, const float* __restrict__ rois,
    float* __restrict__ out, int total)
{
    int idx = blockIdx.x * blockDim.x + threadIdx.x;
    if (idx >= total) return;
    int pw = idx % POOLED;
    int ph = (idx / POOLED) % POOLED;
    int c  = (idx / (POOLED * POOLED)) % C_;
    int n  = idx / (POOLED * POOLED * C_);
    const float* r = rois + n * 5;
    int b  = (int)r[0];
    int x1 = (int)(r[1] * SCALE);
    int y1 = (int)(r[2] * SCALE);
    int x2 = (int)(r[3] * SCALE);
    int y2 = (int)(r[4] * SCALE);
    int rh = y2 - y1 + 1;
    int rw = x2 - x1 + 1;
    int hs = y1 + (ph * rh) / POOLED;
    int he = y1 + ((ph + 1) * rh + POOLED - 1) / POOLED;
    int ws = x1 + (pw * rw) / POOLED;
    int we = x1 + ((pw + 1) * rw + POOLED - 1) / POOLED;
    const float* plane = feat + ((size_t)b * C_ + c) * (size_t)S_;
    float m = -INFINITY;
    for (int h = hs; h < he; ++h) {
        const float* row = plane + h * W_;
        for (int w = ws; w < we; ++w) m = fmaxf(m, row[w]);
    }
    out[idx] = m;
}

extern "C" void kernel_launch(void* const* d_in, const int* in_sizes, int n_in,
                              void* d_out, int out_size, void* d_ws, size_t ws_size,
                              hipStream_t stream) {
    const float* feat = (const float*)d_in[0];
    const float* rois = (const float*)d_in[1];
    float* out = (float*)d_out;

    int N = in_sizes[1] / 5;
    size_t featElems = (size_t)4 * S_ * C_;
    size_t need = (featElems + (size_t)N * NCELL * C_) * sizeof(float);

    if (ws_size >= need && N == 256) {
        float* t   = (float*)d_ws;
        float* ws2 = (float*)d_ws + featElems;

        dim3 tgrid(S_ / 64, C_ / 64, 4);
        nhwc_kernel<<<tgrid, 1024, 0, stream>>>(feat, t);

        pool_kernel<<<3136, 256, 0, stream>>>(t, rois, ws2);

        dim3 ogrid(N, C_ / 64);
        outt_kernel<<<ogrid, 256, 0, stream>>>(ws2, out);
    } else {
        int total = N * C_ * POOLED * POOLED;
        roipool_direct_kernel<<<(total + 255) / 256, 256, 0, stream>>>(feat, rois, out, total);
    }
}

// Round 10
// 34.819 us; speedup vs baseline: 2.4238x; 1.0289x over previous
//
#include <hip/hip_runtime.h>
#include <math.h>

#define POOLED 7
#define SCALE 0.0625f
#define C_ 256
#define H_ 56
#define W_ 56
#define S_ (H_ * W_)   // 3136
#define NCELL 49

typedef _Float16 f16x4 __attribute__((ext_vector_type(4)));

__device__ __forceinline__ f16x4 max4h(f16x4 a, f16x4 b) {
    f16x4 r;
    r[0] = a[0] > b[0] ? a[0] : b[0];
    r[1] = a[1] > b[1] ? a[1] : b[1];
    r[2] = a[2] > b[2] ? a[2] : b[2];
    r[3] = a[3] > b[3] ? a[3] : b[3];
    return r;
}

// ---------- Kernel 1: NCHW fp32 -> NHWC fp16 transpose ----------
// grid = (S/64, C/64, B), 1024 threads, 64x64 tile.
__global__ __launch_bounds__(1024) void nhwc_kernel(
    const float* __restrict__ src, _Float16* __restrict__ dst)
{
    __shared__ float tile[64][65];
    int b = blockIdx.z;
    int sbase = blockIdx.x * 64;
    int cbase = blockIdx.y * 64;
    int tid = threadIdx.x;

    const float* s0 = src + (size_t)b * C_ * S_;
    _Float16* d0 = dst + (size_t)b * S_ * C_;

    {
        int si = tid & 15;         // s-quad
        int c  = tid >> 4;         // 0..63
        float4 v = *(const float4*)(s0 + (size_t)(cbase + c) * S_ + sbase + 4 * si);
        tile[4 * si + 0][c] = v.x;
        tile[4 * si + 1][c] = v.y;
        tile[4 * si + 2][c] = v.z;
        tile[4 * si + 3][c] = v.w;
    }
    __syncthreads();
    {
        int cj = tid & 15;         // c-quad
        int s  = tid >> 4;         // 0..63
        f16x4 pk;
        pk[0] = (_Float16)tile[s][4 * cj + 0];
        pk[1] = (_Float16)tile[s][4 * cj + 1];
        pk[2] = (_Float16)tile[s][4 * cj + 2];
        pk[3] = (_Float16)tile[s][4 * cj + 3];
        *(f16x4*)(d0 + (size_t)(sbase + s) * C_ + cbase + 4 * cj) = pk;
    }
}

// ---------- Kernel 2: pool from fp16 NHWC. wave = one (n, cell) task ----------
// lane = c-quad (f16x4 = 8B). XCD swizzle keeps cells of one RoI on one XCD.
// 2-row x 4-col batches: 8 independent 512B wave-loads, packed-half max chains.
__global__ __launch_bounds__(256) void pool_kernel(
    const _Float16* __restrict__ t, const float* __restrict__ rois,
    float* __restrict__ ws2)
{
    int bid  = blockIdx.x;
    int swz  = (bid & 7) * 392 + (bid >> 3);          // bijective XCD chunking
    int task = (threadIdx.x >> 6) * 3136 + swz;       // [0, 12544)
    int lane = threadIdx.x & 63;

    int n    = task / NCELL;
    int cell = task % NCELL;
    int ph = cell / POOLED;
    int pw = cell % POOLED;

    const float* r = rois + n * 5;
    int b  = (int)r[0];
    int x1 = (int)(r[1] * SCALE);
    int y1 = (int)(r[2] * SCALE);
    int x2 = (int)(r[3] * SCALE);
    int y2 = (int)(r[4] * SCALE);
    int rh = y2 - y1 + 1;
    int rw = x2 - x1 + 1;

    int hs = y1 + (ph * rh) / POOLED;
    int he = y1 + ((ph + 1) * rh + POOLED - 1) / POOLED;
    int ws = x1 + (pw * rw) / POOLED;
    int we = x1 + ((pw + 1) * rw + POOLED - 1) / POOLED;
    int nh = he - hs;
    int nw = we - ws;

    const f16x4* p0 = (const f16x4*)(t + (size_t)b * S_ * C_) + lane
                      + (size_t)(hs * W_ + ws) * 64;

    const _Float16 NEGV = (_Float16)(-65504.0f);
    f16x4 a0 = {NEGV, NEGV, NEGV, NEGV};
    f16x4 a1 = a0, a2 = a0, a3 = a0, a4 = a0, a5 = a0, a6 = a0, a7 = a0;

    for (int h = 0; h < nh; h += 2) {
        int h1 = (h + 1 < nh) ? h + 1 : h;
        const f16x4* hp0 = p0 + (size_t)h  * (W_ * 64);
        const f16x4* hp1 = p0 + (size_t)h1 * (W_ * 64);
        for (int w = 0; w < nw; w += 4) {
            int w1 = (w + 1 < nw) ? w + 1 : w;
            int w2 = (w + 2 < nw) ? w + 2 : w;
            int w3 = (w + 3 < nw) ? w + 3 : w;
            a0 = max4h(a0, hp0[(size_t)w  * 64]);
            a1 = max4h(a1, hp0[(size_t)w1 * 64]);
            a2 = max4h(a2, hp0[(size_t)w2 * 64]);
            a3 = max4h(a3, hp0[(size_t)w3 * 64]);
            a4 = max4h(a4, hp1[(size_t)w  * 64]);
            a5 = max4h(a5, hp1[(size_t)w1 * 64]);
            a6 = max4h(a6, hp1[(size_t)w2 * 64]);
            a7 = max4h(a7, hp1[(size_t)w3 * 64]);
        }
    }
    f16x4 m = max4h(max4h(max4h(a0, a1), max4h(a2, a3)),
                    max4h(max4h(a4, a5), max4h(a6, a7)));

    float4 acc = make_float4((float)m[0], (float)m[1], (float)m[2], (float)m[3]);
    *((float4*)(ws2 + (size_t)task * C_) + lane) = acc;
}

// ---------- Kernel 3: per-n output transpose (cell, c) -> (c, cell) ----------
// grid = (N, C/64), 256 threads. LDS tile [64 c][49 cell] padded.
__global__ __launch_bounds__(256) void outt_kernel(
    const float* __restrict__ ws2, float* __restrict__ out)
{
    __shared__ float tile[64][51];
    int n = blockIdx.x;
    int cbase = blockIdx.y * 64;
    int tid = threadIdx.x;

    const float* src = ws2 + (size_t)n * NCELL * C_;
    int cl = tid & 63;
    int cell0 = tid >> 6;
    #pragma unroll
    for (int k = 0; k < 13; ++k) {
        int cell = cell0 + 4 * k;
        if (cell < NCELL) tile[cl][cell] = src[(size_t)cell * C_ + cbase + cl];
    }
    __syncthreads();
    float* dst = out + (size_t)n * C_ * NCELL + (size_t)cbase * NCELL;
    #pragma unroll
    for (int k = 0; k < 13; ++k) {
        int f = tid + 256 * k;
        if (f < 64 * NCELL) {
            int c = f / NCELL, cell = f % NCELL;
            dst[f] = tile[c][cell];
        }
    }
}

// ---------- Fallback if workspace too small ----------
__global__ __launch_bounds__(256) void roipool_direct_kernel(
    const float* __restrict__ feat, const float* __restrict__ rois,
    float* __restrict__ out, int total)
{
    int idx = blockIdx.x * blockDim.x + threadIdx.x;
    if (idx >= total) return;
    int pw = idx % POOLED;
    int ph = (idx / POOLED) % POOLED;
    int c  = (idx / (POOLED * POOLED)) % C_;
    int n  = idx / (POOLED * POOLED * C_);
    const float* r = rois + n * 5;
    int b  = (int)r[0];
    int x1 = (int)(r[1] * SCALE);
    int y1 = (int)(r[2] * SCALE);
    int x2 = (int)(r[3] * SCALE);
    int y2 = (int)(r[4] * SCALE);
    int rh = y2 - y1 + 1;
    int rw = x2 - x1 + 1;
    int hs = y1 + (ph * rh) / POOLED;
    int he = y1 + ((ph + 1) * rh + POOLED - 1) / POOLED;
    int ws = x1 + (pw * rw) / POOLED;
    int we = x1 + ((pw + 1) * rw + POOLED - 1) / POOLED;
    const float* plane = feat + ((size_t)b * C_ + c) * (size_t)S_;
    float m = -INFINITY;
    for (int h = hs; h < he; ++h) {
        const float* row = plane + h * W_;
        for (int w = ws; w < we; ++w) m = fmaxf(m, row[w]);
    }
    out[idx] = m;
}

extern "C" void kernel_launch(void* const* d_in, const int* in_sizes, int n_in,
                              void* d_out, int out_size, void* d_ws, size_t ws_size,
                              hipStream_t stream) {
    const float* feat = (const float*)d_in[0];
    const float* rois = (const float*)d_in[1];
    float* out = (float*)d_out;

    int N = in_sizes[1] / 5;
    size_t featBytes = (size_t)4 * S_ * C_ * sizeof(_Float16);   // 6.4 MB fp16 staging
    size_t need = featBytes + (size_t)N * NCELL * C_ * sizeof(float);

    if (ws_size >= need && N == 256) {
        _Float16* t = (_Float16*)d_ws;
        float* ws2  = (float*)((char*)d_ws + featBytes);

        dim3 tgrid(S_ / 64, C_ / 64, 4);
        nhwc_kernel<<<tgrid, 1024, 0, stream>>>(feat, t);

        pool_kernel<<<3136, 256, 0, stream>>>(t, rois, ws2);

        dim3 ogrid(N, C_ / 64);
        outt_kernel<<<ogrid, 256, 0, stream>>>(ws2, out);
    } else {
        int total = N * C_ * POOLED * POOLED;
        roipool_direct_kernel<<<(total + 255) / 256, 256, 0, stream>>>(feat, rois, out, total);
    }
}

// Round 11
// 31.373 us; speedup vs baseline: 2.6900x; 1.1098x over previous
//
#include <hip/hip_runtime.h>
#include <math.h>

#define POOLED 7
#define SCALE 0.0625f
#define C_ 256
#define H_ 56
#define W_ 56
#define S_ (H_ * W_)   // 3136
#define NCELL 49

typedef _Float16 f16x4 __attribute__((ext_vector_type(4)));

__device__ __forceinline__ f16x4 max4h(f16x4 a, f16x4 b) {
    f16x4 r;
    r[0] = a[0] > b[0] ? a[0] : b[0];
    r[1] = a[1] > b[1] ? a[1] : b[1];
    r[2] = a[2] > b[2] ? a[2] : b[2];
    r[3] = a[3] > b[3] ? a[3] : b[3];
    return r;
}

// ---------- Kernel 1: NCHW fp32 -> NHWC fp16 transpose ----------
// grid = (S/64, C/64, B), 1024 threads, 64x64 tile.
__global__ __launch_bounds__(1024) void nhwc_kernel(
    const float* __restrict__ src, _Float16* __restrict__ dst)
{
    __shared__ float tile[64][65];
    int b = blockIdx.z;
    int sbase = blockIdx.x * 64;
    int cbase = blockIdx.y * 64;
    int tid = threadIdx.x;

    const float* s0 = src + (size_t)b * C_ * S_;
    _Float16* d0 = dst + (size_t)b * S_ * C_;

    {
        int si = tid & 15;         // s-quad
        int c  = tid >> 4;         // 0..63
        float4 v = *(const float4*)(s0 + (size_t)(cbase + c) * S_ + sbase + 4 * si);
        tile[4 * si + 0][c] = v.x;
        tile[4 * si + 1][c] = v.y;
        tile[4 * si + 2][c] = v.z;
        tile[4 * si + 3][c] = v.w;
    }
    __syncthreads();
    {
        int cj = tid & 15;         // c-quad
        int s  = tid >> 4;         // 0..63
        f16x4 pk;
        pk[0] = (_Float16)tile[s][4 * cj + 0];
        pk[1] = (_Float16)tile[s][4 * cj + 1];
        pk[2] = (_Float16)tile[s][4 * cj + 2];
        pk[3] = (_Float16)tile[s][4 * cj + 3];
        *(f16x4*)(d0 + (size_t)(sbase + s) * C_ + cbase + 4 * cj) = pk;
    }
}

// ---------- Kernel 2: fused pool + output write ----------
// grid = 3328 blocks (= 256 n x 13 cell-groups), 256 threads = 4 waves.
// Wave wv pools cell cg*4+wv (all 256 channels, f16x4/lane); results staged in
// LDS then written to out[n, c, cg*4..+3] as 16B-contiguous runs.
// XCD swizzle (3328 = 8*416) keeps all 13 blocks of an n on one XCD ->
// read locality + partial output lines accumulate in that L2.
__global__ __launch_bounds__(256) void pool_fused_kernel(
    const _Float16* __restrict__ t, const float* __restrict__ rois,
    float* __restrict__ out)
{
    __shared__ float stage[4][257];
    int b0   = blockIdx.x;
    int swz  = (b0 & 7) * 416 + (b0 >> 3);   // bijective XCD chunking
    int n    = swz / 13;
    int cg   = swz % 13;
    int wv   = threadIdx.x >> 6;
    int lane = threadIdx.x & 63;
    int cell = cg * 4 + wv;

    const float* r = rois + n * 5;
    int b  = (int)r[0];
    int x1 = (int)(r[1] * SCALE);
    int y1 = (int)(r[2] * SCALE);
    int x2 = (int)(r[3] * SCALE);
    int y2 = (int)(r[4] * SCALE);
    int rh = y2 - y1 + 1;
    int rw = x2 - x1 + 1;

    if (cell < NCELL) {
        int ph = cell / POOLED;
        int pw = cell % POOLED;
        int hs = y1 + (ph * rh) / POOLED;
        int he = y1 + ((ph + 1) * rh + POOLED - 1) / POOLED;
        int ws = x1 + (pw * rw) / POOLED;
        int we = x1 + ((pw + 1) * rw + POOLED - 1) / POOLED;
        int nh = he - hs;
        int nw = we - ws;

        const f16x4* p0 = (const f16x4*)(t + (size_t)b * S_ * C_) + lane
                          + (size_t)(hs * W_ + ws) * 64;

        const _Float16 NEGV = (_Float16)(-65504.0f);
        f16x4 a0 = {NEGV, NEGV, NEGV, NEGV};
        f16x4 a1 = a0, a2 = a0, a3 = a0, a4 = a0, a5 = a0, a6 = a0, a7 = a0;

        for (int h = 0; h < nh; h += 2) {
            int h1 = (h + 1 < nh) ? h + 1 : h;
            const f16x4* hp0 = p0 + (size_t)h  * (W_ * 64);
            const f16x4* hp1 = p0 + (size_t)h1 * (W_ * 64);
            for (int w = 0; w < nw; w += 4) {
                int w1 = (w + 1 < nw) ? w + 1 : w;
                int w2 = (w + 2 < nw) ? w + 2 : w;
                int w3 = (w + 3 < nw) ? w + 3 : w;
                a0 = max4h(a0, hp0[(size_t)w  * 64]);
                a1 = max4h(a1, hp0[(size_t)w1 * 64]);
                a2 = max4h(a2, hp0[(size_t)w2 * 64]);
                a3 = max4h(a3, hp0[(size_t)w3 * 64]);
                a4 = max4h(a4, hp1[(size_t)w  * 64]);
                a5 = max4h(a5, hp1[(size_t)w1 * 64]);
                a6 = max4h(a6, hp1[(size_t)w2 * 64]);
                a7 = max4h(a7, hp1[(size_t)w3 * 64]);
            }
        }
        f16x4 m = max4h(max4h(max4h(a0, a1), max4h(a2, a3)),
                        max4h(max4h(a4, a5), max4h(a6, a7)));

        stage[wv][4 * lane + 0] = (float)m[0];
        stage[wv][4 * lane + 1] = (float)m[1];
        stage[wv][4 * lane + 2] = (float)m[2];
        stage[wv][4 * lane + 3] = (float)m[3];
    }
    __syncthreads();

    float* dst = out + (size_t)n * C_ * NCELL + cg * 4;
    int nc = (cg < 12) ? 4 : 1;
    if (nc == 4) {
        // 1024 elems: thread f -> c = f>>2, j = f&3; 16B-contiguous runs.
        #pragma unroll
        for (int k = 0; k < 4; ++k) {
            int f = threadIdx.x + 256 * k;
            int c = f >> 2, j = f & 3;
            dst[(size_t)c * NCELL + j] = stage[j][c];
        }
    } else {
        int c = threadIdx.x;
        dst[(size_t)c * NCELL] = stage[0][c];
    }
}

// ---------- Fallback if workspace too small ----------
__global__ __launch_bounds__(256) void roipool_direct_kernel(
    const float* __restrict__ feat, const float* __restrict__ rois,
    float* __restrict__ out, int total)
{
    int idx = blockIdx.x * blockDim.x + threadIdx.x;
    if (idx >= total) return;
    int pw = idx % POOLED;
    int ph = (idx / POOLED) % POOLED;
    int c  = (idx / (POOLED * POOLED)) % C_;
    int n  = idx / (POOLED * POOLED * C_);
    const float* r = rois + n * 5;
    int b  = (int)r[0];
    int x1 = (int)(r[1] * SCALE);
    int y1 = (int)(r[2] * SCALE);
    int x2 = (int)(r[3] * SCALE);
    int y2 = (int)(r[4] * SCALE);
    int rh = y2 - y1 + 1;
    int rw = x2 - x1 + 1;
    int hs = y1 + (ph * rh) / POOLED;
    int he = y1 + ((ph + 1) * rh + POOLED - 1) / POOLED;
    int ws = x1 + (pw * rw) / POOLED;
    int we = x1 + ((pw + 1) * rw + POOLED - 1) / POOLED;
    const float* plane = feat + ((size_t)b * C_ + c) * (size_t)S_;
    float m = -INFINITY;
    for (int h = hs; h < he; ++h) {
        const float* row = plane + h * W_;
        for (int w = ws; w < we; ++w) m = fmaxf(m, row[w]);
    }
    out[idx] = m;
}

extern "C" void kernel_launch(void* const* d_in, const int* in_sizes, int n_in,
                              void* d_out, int out_size, void* d_ws, size_t ws_size,
                              hipStream_t stream) {
    const float* feat = (const float*)d_in[0];
    const float* rois = (const float*)d_in[1];
    float* out = (float*)d_out;

    int N = in_sizes[1] / 5;
    size_t featBytes = (size_t)4 * S_ * C_ * sizeof(_Float16);   // 6.4 MB fp16 staging

    if (ws_size >= featBytes && N == 256) {
        _Float16* t = (_Float16*)d_ws;

        dim3 tgrid(S_ / 64, C_ / 64, 4);
        nhwc_kernel<<<tgrid, 1024, 0, stream>>>(feat, t);

        pool_fused_kernel<<<3328, 256, 0, stream>>>(t, rois, out);
    } else {
        int total = N * C_ * POOLED * POOLED;
        roipool_direct_kernel<<<(total + 255) / 256, 256, 0, stream>>>(feat, rois, out, total);
    }
}